// Round 5
// baseline (395.063 us; speedup 1.0000x reference)
//
#include <hip/hip_runtime.h>

typedef __bf16 bf16;
typedef bf16 bf16x2 __attribute__((ext_vector_type(2)));
typedef bf16 bf16x4 __attribute__((ext_vector_type(4)));
typedef bf16 bf16x8 __attribute__((ext_vector_type(8)));
typedef float floatx4 __attribute__((ext_vector_type(4)));
typedef float floatx16 __attribute__((ext_vector_type(16)));
typedef unsigned int uintx4 __attribute__((ext_vector_type(4)));

__device__ __forceinline__ floatx4 mfma16(bf16x8 a, bf16x8 b, floatx4 c) {
  return __builtin_amdgcn_mfma_f32_16x16x32_bf16(a, b, c, 0, 0, 0);
}
__device__ __forceinline__ floatx16 mfma32(bf16x8 a, bf16x8 b, floatx16 c) {
  return __builtin_amdgcn_mfma_f32_32x32x16_bf16(a, b, c, 0, 0, 0);
}

__device__ __forceinline__ void async_ld16(const bf16* g, bf16* lds) {
  __builtin_amdgcn_global_load_lds(
      (const __attribute__((address_space(1))) void*)g,
      (__attribute__((address_space(3))) void*)lds, 16, 0, 0);
}

// ---- fused prep: convert x||ctx -> kvin bf16, + transpose Wq/Wkv/Wo -> bf16
__global__ __launch_bounds__(256) void prep(
    const float* __restrict__ x, const float* __restrict__ ctx,
    const float* __restrict__ Wq, const float* __restrict__ Wkv,
    const float* __restrict__ Wo, bf16* __restrict__ kvin,
    bf16* __restrict__ WT, bf16* __restrict__ WoT) {
  __shared__ float tile[32][33];
  int bid = blockIdx.x;
  if (bid < 6144) {
    int idx = bid * 256 + threadIdx.x;
    int row = idx >> 8;
    int c4 = (idx & 255) << 2;
    int b = row / 3072, l = row - b * 3072;
    const float* src = (l < 2048)
        ? (x + ((size_t)b * 2048 + l) * 1024 + c4)
        : (ctx + ((size_t)b * 1024 + (l - 2048)) * 1024 + c4);
    float4 v = *(const float4*)src;
    bf16x4 o = { (bf16)v.x, (bf16)v.y, (bf16)v.z, (bf16)v.w };
    *(bf16x4*)(kvin + (size_t)row * 1024 + c4) = o;
    return;
  }
  const float* W; bf16* OT; int N, t;
  if (bid < 7168)      { W = Wq;  OT = WT;                        N = 1024; t = bid - 6144; }
  else if (bid < 9216) { W = Wkv; OT = WT + (size_t)1024 * 1024;  N = 2048; t = bid - 7168; }
  else                 { W = Wo;  OT = WoT;                       N = 1024; t = bid - 9216; }
  int nb = N >> 5;
  int n0 = (t % nb) * 32, k0 = (t / nb) * 32;
  int tx = threadIdx.x & 31, ty = threadIdx.x >> 5;
  for (int i = 0; i < 4; i++) {
    int kk = ty + i * 8;
    tile[kk][tx] = W[(size_t)(k0 + kk) * N + n0 + tx];
  }
  __syncthreads();
  for (int i = 0; i < 4; i++) {
    int nn = ty + i * 8;
    OT[(size_t)(n0 + nn) * 1024 + k0 + tx] = (bf16)tile[tx][nn];
  }
}

// ---- C[M,N] = A[M,K] @ Bt[N,K]^T (+ bias)
// MODE 1 (fused QKV, K=1024): N=3072. col<1024 -> Qb (scaled 0.125*log2e, self
//   rows only). 1024..2047 -> Kb. >=2048 -> Vt transposed [2][1024][3072].
// MODE 3 (O-proj split-K): blockIdx.z picks K-half [z*512,z*512+512); raw fp32
//   partial to out0/out1 (no bias).
template <int MODE>
__global__ __launch_bounds__(256) void gemm_bt(
    const bf16* __restrict__ A, const bf16* __restrict__ Bt,
    const float* __restrict__ bias0, const float* __restrict__ bias1,
    void* __restrict__ out0, void* __restrict__ out1, void* __restrict__ out2,
    int N, int K) {
  int row0 = blockIdx.x * 128, col0 = blockIdx.y * 128;
  if constexpr (MODE == 1) {
    if (col0 < 1024 && (row0 % 3072) >= 2048) return;  // ctx rows have no Q
  }
  __shared__ bf16 As[128 * 32];
  __shared__ bf16 Bs[128 * 32];
  int tid = threadIdx.x;
  int wave = tid >> 6, lane = tid & 63;
  int lane15 = lane & 15, quad = lane >> 4;
  int wm = (wave & 1) * 64, wn = (wave >> 1) * 64;
  int rA = lane >> 2;
  int cA = (lane & 3) * 8;
  int kbeg = 0, kend = K;
  if constexpr (MODE == 3) { kbeg = blockIdx.z * 512; kend = kbeg + 512; }
  floatx4 acc[4][4] = {};
  for (int k0 = kbeg; k0 < kend; k0 += 32) {
    for (int j = 0; j < 2; j++) {
      int chunk = wave * 2 + j;
      async_ld16(A + (size_t)(row0 + chunk * 16 + rA) * K + k0 + cA,
                 &As[chunk * 512]);
      async_ld16(Bt + (size_t)(col0 + chunk * 16 + rA) * K + k0 + cA,
                 &Bs[chunk * 512]);
    }
    __syncthreads();
    bf16x8 af[4], bfr[4];
    for (int t = 0; t < 4; t++)
      af[t] = *(const bf16x8*)(&As[(wm + t * 16 + lane15) * 32 + quad * 8]);
    for (int t = 0; t < 4; t++)
      bfr[t] = *(const bf16x8*)(&Bs[(wn + t * 16 + lane15) * 32 + quad * 8]);
    for (int tm = 0; tm < 4; tm++)
      for (int tn = 0; tn < 4; tn++)
        acc[tm][tn] = mfma16(af[tm], bfr[tn], acc[tm][tn]);
    __syncthreads();
  }
  if constexpr (MODE == 3) {
    float* P = (blockIdx.z == 0) ? (float*)out0 : (float*)out1;
    for (int tm = 0; tm < 4; tm++)
      for (int r = 0; r < 4; r++) {
        size_t grow = row0 + wm + tm * 16 + quad * 4 + r;
        for (int tn = 0; tn < 4; tn++)
          P[grow * N + col0 + wn + tn * 16 + lane15] = acc[tm][tn][r];
      }
  } else {
    float bv[4];
    for (int tn = 0; tn < 4; tn++) {
      int col = col0 + wn + tn * 16 + lane15;
      bv[tn] = (col < 1024) ? bias0[col] : bias1[col - 1024];
    }
    int bb = row0 / 3072;
    int l0 = row0 - bb * 3072;
    if (col0 < 1024) {           // Q
      const float SQ = 0.18033688011f;  // 0.125 * log2(e)
      bf16* O = (bf16*)out0;
      for (int tm = 0; tm < 4; tm++)
        for (int r = 0; r < 4; r++) {
          size_t grow = (size_t)bb * 2048 + l0 + wm + tm * 16 + quad * 4 + r;
          for (int tn = 0; tn < 4; tn++)
            O[grow * 1024 + col0 + wn + tn * 16 + lane15] =
                (bf16)((acc[tm][tn][r] + bv[tn]) * SQ);
        }
    } else if (col0 < 2048) {    // K
      bf16* O = (bf16*)out1;
      for (int tm = 0; tm < 4; tm++)
        for (int r = 0; r < 4; r++) {
          size_t grow = row0 + wm + tm * 16 + quad * 4 + r;
          for (int tn = 0; tn < 4; tn++)
            O[grow * 1024 + (col0 - 1024) + wn + tn * 16 + lane15] =
                (bf16)(acc[tm][tn][r] + bv[tn]);
        }
    } else {                     // V, transposed
      bf16* V = (bf16*)out2;
      for (int tm = 0; tm < 4; tm++) {
        int lr = l0 + wm + tm * 16 + quad * 4;
        for (int tn = 0; tn < 4; tn++) {
          int c = col0 - 2048 + wn + tn * 16 + lane15;
          bf16x4 pk = { (bf16)(acc[tm][tn][0] + bv[tn]),
                        (bf16)(acc[tm][tn][1] + bv[tn]),
                        (bf16)(acc[tm][tn][2] + bv[tn]),
                        (bf16)(acc[tm][tn][3] + bv[tn]) };
          *(bf16x4*)(V + ((size_t)bb * 1024 + c) * 3072 + lr) = pk;
        }
      }
    }
  }
}

// ---- O-proj merge: out = P0 + P1 + bias
__global__ __launch_bounds__(256) void oproj_merge(
    const float* __restrict__ P0, const float* __restrict__ P1,
    const float* __restrict__ bo, float* __restrict__ out) {
  int i = blockIdx.x * 256 + threadIdx.x;   // one float4 per thread
  float4 a = ((const float4*)P0)[i];
  float4 b = ((const float4*)P1)[i];
  float4 c = ((const float4*)bo)[i & 255];
  float4 o = { a.x + b.x + c.x, a.y + b.y + c.y,
               a.z + b.z + c.z, a.w + b.w + c.w };
  ((float4*)out)[i] = o;
}

// ---- flash attention v3: Br=64, wave key-split, l-via-MFMA.
// 4 waves = (qsub 0/1) x (key-group 0/1). Fixed-ref softmax (m=0) => linear
// merge of partial (O, l) via LDS overlay. l accumulated by MFMA against a
// ones B-frag: row-sum layout == Oacc layout (no shuffles). Grid = b*h*32.
__global__ __launch_bounds__(256, 4) void flash_attn(
    const bf16* __restrict__ Qb, const bf16* __restrict__ Kb,
    const bf16* __restrict__ Vt, bf16* __restrict__ Ob) {
  const int LD = 72;
  __shared__ bf16 Ks[2][64 * LD];   // [grp][key][dh]
  __shared__ bf16 Vs[2][64 * LD];   // [grp][dh][key]
  int tid = threadIdx.x;
  int wave = tid >> 6, lane = tid & 63;
  int qsub = wave & 1, grp = wave >> 1;
  int l31 = lane & 31, half = lane >> 5;
  int blk = blockIdx.x;
  int qt = 31 - (blk & 31);      // longest first
  int h = (blk >> 5) & 15, b = blk >> 9;
  int q0 = qt * 64;
  int qw0 = q0 + qsub * 32;
  int qq = qw0 + l31;            // this lane's q (col of S^T)

  const bf16* qrow = Qb + ((size_t)(b * 2048 + qq)) * 1024 + h * 64 + half * 8;
  bf16x8 qf[4];
  for (int c = 0; c < 4; c++) qf[c] = *(const bf16x8*)(qrow + c * 16);

  const bf16 one = (bf16)1.0f;
  const bf16x8 onesf = {one, one, one, one, one, one, one, one};

  floatx16 Oacc[2] = {};
  floatx16 l_acc = {};

  int nself = qt + 1;            // 64-key self tiles
  int T = nself + 16;
  int iters = (T + 1 - grp) >> 1;
  int max_iters = (T + 1) >> 1;
  const bf16* kbase = Kb + (size_t)(b * 3072) * 1024 + h * 64;
  const bf16* vbase = Vt + ((size_t)b * 1024 + h * 64) * 3072;

  // staging by the group's 128 threads: 2 threads/row, 32 elems (4x bf16x8)
  int tidg = qsub * 64 + lane;
  int sr = tidg >> 1, sc = (tidg & 1) * 32;
  bf16x8 kreg[4], vreg[4];
  auto prefetch = [&](int kr) {
    const bf16* kp = kbase + (size_t)(kr + sr) * 1024 + sc;
    const bf16* vp = vbase + (size_t)sr * 3072 + kr + sc;
    for (int j = 0; j < 4; j++) {
      kreg[j] = *(const bf16x8*)(kp + j * 8);
      vreg[j] = *(const bf16x8*)(vp + j * 8);
    }
  };
  int t = grp;
  int keyrow = (t < nself) ? t * 64 : 2048 + (t - nself) * 64;
  prefetch(keyrow);

  bf16* ksg = &Ks[grp][0];
  bf16* vsg = &Vs[grp][0];
  for (int it = 0; it < max_iters; it++) {
    bool act = it < iters;
    bool is_self = t < nself;
    int cur = keyrow;
    __syncthreads();
    if (act)
      for (int j = 0; j < 4; j++) {
        *(bf16x8*)(&ksg[sr * LD + sc + j * 8]) = kreg[j];
        *(bf16x8*)(&vsg[sr * LD + sc + j * 8]) = vreg[j];
      }
    __syncthreads();
    t += 2;
    keyrow = (t < nself) ? t * 64 : 2048 + (t - nself) * 64;
    if (act && t < T) prefetch(keyrow);
    if (act) {
      uintx4 pf[4];
      for (int kt = 0; kt < 2; kt++) {
        floatx16 st = {};
        const bf16* ka = &ksg[(kt * 32 + l31) * LD + half * 8];
        for (int c = 0; c < 4; c++)
          st = mfma32(*(const bf16x8*)(ka + c * 16), qf[c], st);
        bool need_mask = is_self && (cur + kt * 32 + 31 > qw0);
        float p[16];
        for (int r = 0; r < 16; r++) {
          float e = __builtin_amdgcn_exp2f(st[r]);
          if (need_mask) {
            int key = cur + kt * 32 + (r & 3) + 8 * (r >> 2) + half * 4;
            if (key > qq) e = 0.f;
          }
          p[r] = e;
        }
        unsigned pk[8];
        for (int m2 = 0; m2 < 8; m2++) {
          bf16x2 two = { (bf16)p[2 * m2], (bf16)p[2 * m2 + 1] };
          pk[m2] = __builtin_bit_cast(unsigned, two);
        }
        for (int c2 = 0; c2 < 2; c2++) {
          unsigned a0 = pk[4 * c2 + 0], a1 = pk[4 * c2 + 1];
          unsigned a2 = pk[4 * c2 + 2], a3 = pk[4 * c2 + 3];
          unsigned sA = (unsigned)__shfl_xor((int)(half ? a0 : a2), 32, 64);
          unsigned sB = (unsigned)__shfl_xor((int)(half ? a1 : a3), 32, 64);
          int c = kt * 2 + c2;
          pf[c][0] = half ? sA : a0;
          pf[c][1] = half ? sB : a1;
          pf[c][2] = half ? a2 : sA;
          pf[c][3] = half ? a3 : sB;
        }
      }
      for (int c = 0; c < 4; c++)
        l_acc = mfma32(__builtin_bit_cast(bf16x8, pf[c]), onesf, l_acc);
      for (int vt = 0; vt < 2; vt++) {
        const bf16* va = &vsg[(vt * 32 + l31) * LD + half * 8];
        for (int c = 0; c < 4; c++)
          Oacc[vt] = mfma32(__builtin_bit_cast(bf16x8, pf[c]),
                            *(const bf16x8*)(va + c * 16), Oacc[vt]);
      }
    }
  }
  // ---- merge the two key-groups (linear: fixed softmax reference)
  __syncthreads();              // all compute done; LDS reusable
  float* Mb = (float*)&Ks[0][0];        // [qsub][vt][r][lane]  16 KB
  float* Ml = (float*)&Vs[0][0];        // [qsub][r][lane]       8 KB
  if (grp == 1) {
    for (int vt = 0; vt < 2; vt++)
      for (int r = 0; r < 16; r++)
        Mb[((qsub * 2 + vt) * 16 + r) * 64 + lane] = Oacc[vt][r];
    for (int r = 0; r < 16; r++)
      Ml[(qsub * 16 + r) * 64 + lane] = l_acc[r];
  }
  __syncthreads();
  if (grp == 0) {
    for (int vt = 0; vt < 2; vt++)
      for (int r = 0; r < 16; r++) {
        int qr = (r & 3) + 8 * (r >> 2) + half * 4;
        float lsum = l_acc[r] + Ml[(qsub * 16 + r) * 64 + lane];
        float o = Oacc[vt][r] + Mb[((qsub * 2 + vt) * 16 + r) * 64 + lane];
        Ob[(size_t)(b * 2048 + qw0 + qr) * 1024 + h * 64 + vt * 32 + l31] =
            (bf16)(o / lsum);
      }
  }
}

extern "C" void kernel_launch(void* const* d_in, const int* in_sizes, int n_in,
                              void* d_out, int out_size, void* d_ws,
                              size_t ws_size, hipStream_t stream) {
  const float* x   = (const float*)d_in[0];
  const float* ctx = (const float*)d_in[1];
  const float* Wq  = (const float*)d_in[2];
  const float* bq  = (const float*)d_in[3];
  const float* Wkv = (const float*)d_in[4];
  const float* bkv = (const float*)d_in[5];
  const float* Wo  = (const float*)d_in[6];
  const float* bo  = (const float*)d_in[7];
  float* out = (float*)d_out;

  bf16* p = (bf16*)d_ws;
  bf16* kvin = p;   p += (size_t)6144 * 1024;      // x||context bf16
  bf16* WT   = p;   p += (size_t)3072 * 1024;      // WqT | WkvT
  bf16* WoT  = p;   p += (size_t)1024 * 1024;
  bf16* Qb   = p;   p += (size_t)4096 * 1024;
  bf16* Kb   = p;   p += (size_t)6144 * 1024;
  bf16* Vt   = p;   p += (size_t)2 * 1024 * 3072;  // V transposed [b][dh][l]
  bf16* Ob   = p;
  // O-proj fp32 partials overlay dead regions (each needs 16 MB):
  float* P0 = (float*)kvin;   // kvin+WT = 18.9 MB, dead after QKV GEMM
  float* P1 = (float*)Qb;     // Qb+Kb = 21 MB, dead after flash

  prep<<<10240, 256, 0, stream>>>(x, ctx, Wq, Wkv, Wo, kvin, WT, WoT);
  gemm_bt<1><<<dim3(48, 24), 256, 0, stream>>>(kvin, WT, bq, bkv, Qb, Kb, Vt,
                                               3072, 1024);
  flash_attn<<<1024, 256, 0, stream>>>(Qb, Kb, Vt, Ob);
  gemm_bt<3><<<dim3(32, 8, 2), 256, 0, stream>>>(Ob, WoT, nullptr, nullptr,
                                                 P0, P1, nullptr, 1024, 1024);
  oproj_merge<<<4096, 256, 0, stream>>>(P0, P1, bo, out);
}

// Round 6
// 246.594 us; speedup vs baseline: 1.6021x; 1.6021x over previous
//
#include <hip/hip_runtime.h>

typedef __bf16 bf16;
typedef bf16 bf16x2 __attribute__((ext_vector_type(2)));
typedef bf16 bf16x4 __attribute__((ext_vector_type(4)));
typedef bf16 bf16x8 __attribute__((ext_vector_type(8)));
typedef float floatx4 __attribute__((ext_vector_type(4)));
typedef float floatx16 __attribute__((ext_vector_type(16)));
typedef unsigned int uintx4 __attribute__((ext_vector_type(4)));

__device__ __forceinline__ floatx4 mfma16(bf16x8 a, bf16x8 b, floatx4 c) {
  return __builtin_amdgcn_mfma_f32_16x16x32_bf16(a, b, c, 0, 0, 0);
}
__device__ __forceinline__ floatx16 mfma32(bf16x8 a, bf16x8 b, floatx16 c) {
  return __builtin_amdgcn_mfma_f32_32x32x16_bf16(a, b, c, 0, 0, 0);
}

__device__ __forceinline__ void async_ld16(const bf16* g, bf16* lds) {
  __builtin_amdgcn_global_load_lds(
      (const __attribute__((address_space(1))) void*)g,
      (__attribute__((address_space(3))) void*)lds, 16, 0, 0);
}

// ---- fused prep: convert x||ctx -> kvin bf16, + transpose Wq/Wkv/Wo -> bf16
__global__ __launch_bounds__(256) void prep(
    const float* __restrict__ x, const float* __restrict__ ctx,
    const float* __restrict__ Wq, const float* __restrict__ Wkv,
    const float* __restrict__ Wo, bf16* __restrict__ kvin,
    bf16* __restrict__ WT, bf16* __restrict__ WoT) {
  __shared__ float tile[32][33];
  int bid = blockIdx.x;
  if (bid < 6144) {
    int idx = bid * 256 + threadIdx.x;
    int row = idx >> 8;
    int c4 = (idx & 255) << 2;
    int b = row / 3072, l = row - b * 3072;
    const float* src = (l < 2048)
        ? (x + ((size_t)b * 2048 + l) * 1024 + c4)
        : (ctx + ((size_t)b * 1024 + (l - 2048)) * 1024 + c4);
    float4 v = *(const float4*)src;
    bf16x4 o = { (bf16)v.x, (bf16)v.y, (bf16)v.z, (bf16)v.w };
    *(bf16x4*)(kvin + (size_t)row * 1024 + c4) = o;
    return;
  }
  const float* W; bf16* OT; int N, t;
  if (bid < 7168)      { W = Wq;  OT = WT;                        N = 1024; t = bid - 6144; }
  else if (bid < 9216) { W = Wkv; OT = WT + (size_t)1024 * 1024;  N = 2048; t = bid - 7168; }
  else                 { W = Wo;  OT = WoT;                       N = 1024; t = bid - 9216; }
  int nb = N >> 5;
  int n0 = (t % nb) * 32, k0 = (t / nb) * 32;
  int tx = threadIdx.x & 31, ty = threadIdx.x >> 5;
  for (int i = 0; i < 4; i++) {
    int kk = ty + i * 8;
    tile[kk][tx] = W[(size_t)(k0 + kk) * N + n0 + tx];
  }
  __syncthreads();
  for (int i = 0; i < 4; i++) {
    int nn = ty + i * 8;
    OT[(size_t)(n0 + nn) * 1024 + k0 + tx] = (bf16)tile[tx][nn];
  }
}

// ---- C[M,N] = A[M,K] @ Bt[N,K]^T + bias
// Grid: x = col-blocks (multiple of 8 => each XCD owns a fixed col stripe,
// B-tile stays L2-resident), y = row-blocks.
// MODE 1 (fused QKV): N=3072. col<1024 -> Qb (scaled 0.125*log2e, self rows
//   only). 1024..2047 -> Kb. >=2048 -> Vt transposed [2][1024][3072].
// MODE 2 (O-proj): fp32 out0.
template <int MODE>
__global__ __launch_bounds__(256) void gemm_bt(
    const bf16* __restrict__ A, const bf16* __restrict__ Bt,
    const float* __restrict__ bias0, const float* __restrict__ bias1,
    void* __restrict__ out0, void* __restrict__ out1, void* __restrict__ out2,
    int N, int K) {
  int row0 = blockIdx.y * 128, col0 = blockIdx.x * 128;
  if constexpr (MODE == 1) {
    if (col0 < 1024 && (row0 % 3072) >= 2048) return;  // ctx rows have no Q
  }
  __shared__ bf16 As[128 * 32];
  __shared__ bf16 Bs[128 * 32];
  int tid = threadIdx.x;
  int wave = tid >> 6, lane = tid & 63;
  int lane15 = lane & 15, quad = lane >> 4;
  int wm = (wave & 1) * 64, wn = (wave >> 1) * 64;
  int rA = lane >> 2;
  int cA = (lane & 3) * 8;
  floatx4 acc[4][4] = {};
  for (int k0 = 0; k0 < K; k0 += 32) {
    for (int j = 0; j < 2; j++) {
      int chunk = wave * 2 + j;
      async_ld16(A + (size_t)(row0 + chunk * 16 + rA) * K + k0 + cA,
                 &As[chunk * 512]);
      async_ld16(Bt + (size_t)(col0 + chunk * 16 + rA) * K + k0 + cA,
                 &Bs[chunk * 512]);
    }
    __syncthreads();
    bf16x8 af[4], bfr[4];
    for (int t = 0; t < 4; t++)
      af[t] = *(const bf16x8*)(&As[(wm + t * 16 + lane15) * 32 + quad * 8]);
    for (int t = 0; t < 4; t++)
      bfr[t] = *(const bf16x8*)(&Bs[(wn + t * 16 + lane15) * 32 + quad * 8]);
    for (int tm = 0; tm < 4; tm++)
      for (int tn = 0; tn < 4; tn++)
        acc[tm][tn] = mfma16(af[tm], bfr[tn], acc[tm][tn]);
    __syncthreads();
  }
  float bv[4];
  for (int tn = 0; tn < 4; tn++) {
    int col = col0 + wn + tn * 16 + lane15;
    if constexpr (MODE == 1)
      bv[tn] = (col < 1024) ? bias0[col] : bias1[col - 1024];
    else
      bv[tn] = bias0[col];
  }
  if constexpr (MODE == 2) {
    float* O = (float*)out0;
    for (int tm = 0; tm < 4; tm++)
      for (int r = 0; r < 4; r++) {
        size_t grow = row0 + wm + tm * 16 + quad * 4 + r;
        for (int tn = 0; tn < 4; tn++)
          O[grow * N + col0 + wn + tn * 16 + lane15] = acc[tm][tn][r] + bv[tn];
      }
  } else {
    int bb = row0 / 3072;
    int l0 = row0 - bb * 3072;
    if (col0 < 1024) {           // Q
      const float SQ = 0.18033688011f;  // 0.125 * log2(e)
      bf16* O = (bf16*)out0;
      for (int tm = 0; tm < 4; tm++)
        for (int r = 0; r < 4; r++) {
          size_t grow = (size_t)bb * 2048 + l0 + wm + tm * 16 + quad * 4 + r;
          for (int tn = 0; tn < 4; tn++)
            O[grow * 1024 + col0 + wn + tn * 16 + lane15] =
                (bf16)((acc[tm][tn][r] + bv[tn]) * SQ);
        }
    } else if (col0 < 2048) {    // K
      bf16* O = (bf16*)out1;
      for (int tm = 0; tm < 4; tm++)
        for (int r = 0; r < 4; r++) {
          size_t grow = row0 + wm + tm * 16 + quad * 4 + r;
          for (int tn = 0; tn < 4; tn++)
            O[grow * 1024 + (col0 - 1024) + wn + tn * 16 + lane15] =
                (bf16)(acc[tm][tn][r] + bv[tn]);
        }
    } else {                     // V, transposed
      bf16* V = (bf16*)out2;
      for (int tm = 0; tm < 4; tm++) {
        int lr = l0 + wm + tm * 16 + quad * 4;
        for (int tn = 0; tn < 4; tn++) {
          int c = col0 - 2048 + wn + tn * 16 + lane15;
          bf16x4 pk = { (bf16)(acc[tm][tn][0] + bv[tn]),
                        (bf16)(acc[tm][tn][1] + bv[tn]),
                        (bf16)(acc[tm][tn][2] + bv[tn]),
                        (bf16)(acc[tm][tn][3] + bv[tn]) };
          *(bf16x4*)(V + ((size_t)bb * 1024 + c) * 3072 + lr) = pk;
        }
      }
    }
  }
}

// ---- flash attention (R4 structure): Br=64, intra-block key-split.
// 4 waves = (qsub 0/1) x (key-group 0/1). Fixed-ref softmax (m=0) => linear
// merge of partial (O, l) via LDS overlay.
// XCD swizzle: blk = qt_ord*32 + bh => blk%8 = bh%8, so all 32 q-blocks of
// one (b,h) land on one XCD; its K/V slice (768 KB) stays L2-resident.
__global__ __launch_bounds__(256, 4) void flash_attn(
    const bf16* __restrict__ Qb, const bf16* __restrict__ Kb,
    const bf16* __restrict__ Vt, bf16* __restrict__ Ob) {
  const int LD = 72;
  __shared__ bf16 Ks[2][64 * LD];   // [grp][key][dh]
  __shared__ bf16 Vs[2][64 * LD];   // [grp][dh][key]
  int tid = threadIdx.x;
  int wave = tid >> 6, lane = tid & 63;
  int qsub = wave & 1, grp = wave >> 1;
  int l31 = lane & 31, half = lane >> 5;
  int blk = blockIdx.x;
  int qt = 31 - (blk >> 5);      // longest first; bh in low bits -> same XCD
  int bh = blk & 31;
  int h = bh & 15, b = bh >> 4;
  int q0 = qt * 64;
  int qw0 = q0 + qsub * 32;
  int qq = qw0 + l31;            // this lane's q (col of S^T)

  const bf16* qrow = Qb + ((size_t)(b * 2048 + qq)) * 1024 + h * 64 + half * 8;
  bf16x8 qf[4];
  for (int c = 0; c < 4; c++) qf[c] = *(const bf16x8*)(qrow + c * 16);

  floatx16 Oacc[2] = {};
  float l_part = 0.f;

  int nself = qt + 1;            // 64-key self tiles
  int T = nself + 16;
  int iters = (T + 1 - grp) >> 1;
  int max_iters = (T + 1) >> 1;
  const bf16* kbase = Kb + (size_t)(b * 3072) * 1024 + h * 64;
  const bf16* vbase = Vt + ((size_t)b * 1024 + h * 64) * 3072;

  // staging by the group's 128 threads: 2 threads/row, 32 elems (4x bf16x8)
  int tidg = qsub * 64 + lane;
  int sr = tidg >> 1, sc = (tidg & 1) * 32;
  bf16x8 kreg[4], vreg[4];
  auto prefetch = [&](int t) {
    int keyrow = (t < nself) ? t * 64 : 2048 + (t - nself) * 64;
    const bf16* kp = kbase + (size_t)(keyrow + sr) * 1024 + sc;
    const bf16* vp = vbase + (size_t)sr * 3072 + keyrow + sc;
    for (int j = 0; j < 4; j++) {
      kreg[j] = *(const bf16x8*)(kp + j * 8);
      vreg[j] = *(const bf16x8*)(vp + j * 8);
    }
  };
  int t = grp;
  prefetch(t);

  bf16* ksg = &Ks[grp][0];
  bf16* vsg = &Vs[grp][0];
  for (int it = 0; it < max_iters; it++) {
    bool act = it < iters;
    int keyrow = 0;
    if (act) keyrow = (t < nself) ? t * 64 : 2048 + (t - nself) * 64;
    __syncthreads();
    if (act)
      for (int j = 0; j < 4; j++) {
        *(bf16x8*)(&ksg[sr * LD + sc + j * 8]) = kreg[j];
        *(bf16x8*)(&vsg[sr * LD + sc + j * 8]) = vreg[j];
      }
    __syncthreads();
    if (act && t + 2 < T) prefetch(t + 2);
    if (act) {
      bool is_self = t < nself;
      uintx4 pf[4];
      for (int kt = 0; kt < 2; kt++) {
        floatx16 st = {};
        const bf16* ka = &ksg[(kt * 32 + l31) * LD + half * 8];
        for (int c = 0; c < 4; c++)
          st = mfma32(*(const bf16x8*)(ka + c * 16), qf[c], st);
        bool need_mask = is_self && (keyrow + kt * 32 + 31 > qw0);
        float p[16];
        for (int r = 0; r < 16; r++) {
          float e = __builtin_amdgcn_exp2f(st[r]);
          if (need_mask) {
            int key = keyrow + kt * 32 + (r & 3) + 8 * (r >> 2) + half * 4;
            if (key > qq) e = 0.f;
          }
          p[r] = e;
          l_part += e;
        }
        unsigned pk[8];
        for (int m2 = 0; m2 < 8; m2++) {
          bf16x2 two = { (bf16)p[2 * m2], (bf16)p[2 * m2 + 1] };
          pk[m2] = __builtin_bit_cast(unsigned, two);
        }
        for (int c2 = 0; c2 < 2; c2++) {
          unsigned a0 = pk[4 * c2 + 0], a1 = pk[4 * c2 + 1];
          unsigned a2 = pk[4 * c2 + 2], a3 = pk[4 * c2 + 3];
          unsigned sA = (unsigned)__shfl_xor((int)(half ? a0 : a2), 32, 64);
          unsigned sB = (unsigned)__shfl_xor((int)(half ? a1 : a3), 32, 64);
          int c = kt * 2 + c2;
          pf[c][0] = half ? sA : a0;
          pf[c][1] = half ? sB : a1;
          pf[c][2] = half ? a2 : sA;
          pf[c][3] = half ? a3 : sB;
        }
      }
      for (int vt = 0; vt < 2; vt++) {
        const bf16* va = &vsg[(vt * 32 + l31) * LD + half * 8];
        for (int c = 0; c < 4; c++)
          Oacc[vt] = mfma32(__builtin_bit_cast(bf16x8, pf[c]),
                            *(const bf16x8*)(va + c * 16), Oacc[vt]);
      }
    }
    t += 2;
  }
  // ---- merge the two key-groups (linear: fixed softmax reference)
  float l_tot = l_part + __shfl_xor(l_part, 32, 64);   // full l for q=qw0+l31
  __syncthreads();              // all compute done; Ks region reusable
  float* Mb = (float*)&Ks[0][0];        // [qsub][vt][r][lane]  16 KB
  float* Lg = Mb + 4096;                // [grp][qsub][32]      512 B
  if (grp == 1) {
    for (int vt = 0; vt < 2; vt++)
      for (int r = 0; r < 16; r++)
        Mb[((qsub * 2 + vt) * 16 + r) * 64 + lane] = Oacc[vt][r];
    if (half == 0) Lg[(2 + qsub) * 32 + l31] = l_tot;
  } else if (half == 0) {
    Lg[qsub * 32 + l31] = l_tot;
  }
  __syncthreads();
  if (grp == 0) {
    for (int vt = 0; vt < 2; vt++)
      for (int r = 0; r < 16; r++) {
        int qr = (r & 3) + 8 * (r >> 2) + half * 4;
        float lsum = Lg[qsub * 32 + qr] + Lg[(2 + qsub) * 32 + qr];
        float o = Oacc[vt][r] + Mb[((qsub * 2 + vt) * 16 + r) * 64 + lane];
        Ob[(size_t)(b * 2048 + qw0 + qr) * 1024 + h * 64 + vt * 32 + l31] =
            (bf16)(o / lsum);
      }
  }
}

extern "C" void kernel_launch(void* const* d_in, const int* in_sizes, int n_in,
                              void* d_out, int out_size, void* d_ws,
                              size_t ws_size, hipStream_t stream) {
  const float* x   = (const float*)d_in[0];
  const float* ctx = (const float*)d_in[1];
  const float* Wq  = (const float*)d_in[2];
  const float* bq  = (const float*)d_in[3];
  const float* Wkv = (const float*)d_in[4];
  const float* bkv = (const float*)d_in[5];
  const float* Wo  = (const float*)d_in[6];
  const float* bo  = (const float*)d_in[7];
  float* out = (float*)d_out;

  bf16* p = (bf16*)d_ws;
  bf16* kvin = p;   p += (size_t)6144 * 1024;      // x||context bf16
  bf16* WT   = p;   p += (size_t)3072 * 1024;      // WqT | WkvT
  bf16* WoT  = p;   p += (size_t)1024 * 1024;
  bf16* Qb   = p;   p += (size_t)4096 * 1024;
  bf16* Kb   = p;   p += (size_t)6144 * 1024;
  bf16* Vt   = p;   p += (size_t)2 * 1024 * 3072;  // V transposed [b][dh][l]
  bf16* Ob   = p;

  prep<<<10240, 256, 0, stream>>>(x, ctx, Wq, Wkv, Wo, kvin, WT, WoT);
  // grid x=col (24 % 8 == 0 -> per-XCD col stripes), y=row
  gemm_bt<1><<<dim3(24, 48), 256, 0, stream>>>(kvin, WT, bq, bkv, Qb, Kb, Vt,
                                               3072, 1024);
  flash_attn<<<1024, 256, 0, stream>>>(Qb, Kb, Vt, Ob);
  gemm_bt<2><<<dim3(8, 32), 256, 0, stream>>>(Ob, WoT, bo, nullptr, out,
                                              nullptr, nullptr, 1024, 1024);
}

// Round 7
// 233.705 us; speedup vs baseline: 1.6904x; 1.0552x over previous
//
#include <hip/hip_runtime.h>

typedef __bf16 bf16;
typedef bf16 bf16x2 __attribute__((ext_vector_type(2)));
typedef bf16 bf16x4 __attribute__((ext_vector_type(4)));
typedef bf16 bf16x8 __attribute__((ext_vector_type(8)));
typedef float floatx4 __attribute__((ext_vector_type(4)));
typedef float floatx16 __attribute__((ext_vector_type(16)));
typedef unsigned int uintx4 __attribute__((ext_vector_type(4)));

__device__ __forceinline__ floatx4 mfma16(bf16x8 a, bf16x8 b, floatx4 c) {
  return __builtin_amdgcn_mfma_f32_16x16x32_bf16(a, b, c, 0, 0, 0);
}
__device__ __forceinline__ floatx16 mfma32(bf16x8 a, bf16x8 b, floatx16 c) {
  return __builtin_amdgcn_mfma_f32_32x32x16_bf16(a, b, c, 0, 0, 0);
}

__device__ __forceinline__ void async_ld16(const bf16* g, bf16* lds) {
  __builtin_amdgcn_global_load_lds(
      (const __attribute__((address_space(1))) void*)g,
      (__attribute__((address_space(3))) void*)lds, 16, 0, 0);
}

// ---- fused prep: convert x||ctx -> kvin bf16, + transpose Wq/Wkv/Wo -> bf16
__global__ __launch_bounds__(256) void prep(
    const float* __restrict__ x, const float* __restrict__ ctx,
    const float* __restrict__ Wq, const float* __restrict__ Wkv,
    const float* __restrict__ Wo, bf16* __restrict__ kvin,
    bf16* __restrict__ WT, bf16* __restrict__ WoT) {
  __shared__ float tile[32][33];
  int bid = blockIdx.x;
  if (bid < 6144) {
    int idx = bid * 256 + threadIdx.x;
    int row = idx >> 8;
    int c4 = (idx & 255) << 2;
    int b = row / 3072, l = row - b * 3072;
    const float* src = (l < 2048)
        ? (x + ((size_t)b * 2048 + l) * 1024 + c4)
        : (ctx + ((size_t)b * 1024 + (l - 2048)) * 1024 + c4);
    float4 v = *(const float4*)src;
    bf16x4 o = { (bf16)v.x, (bf16)v.y, (bf16)v.z, (bf16)v.w };
    *(bf16x4*)(kvin + (size_t)row * 1024 + c4) = o;
    return;
  }
  const float* W; bf16* OT; int N, t;
  if (bid < 7168)      { W = Wq;  OT = WT;                        N = 1024; t = bid - 6144; }
  else if (bid < 9216) { W = Wkv; OT = WT + (size_t)1024 * 1024;  N = 2048; t = bid - 7168; }
  else                 { W = Wo;  OT = WoT;                       N = 1024; t = bid - 9216; }
  int nb = N >> 5;
  int n0 = (t % nb) * 32, k0 = (t / nb) * 32;
  int tx = threadIdx.x & 31, ty = threadIdx.x >> 5;
  for (int i = 0; i < 4; i++) {
    int kk = ty + i * 8;
    tile[kk][tx] = W[(size_t)(k0 + kk) * N + n0 + tx];
  }
  __syncthreads();
  for (int i = 0; i < 4; i++) {
    int nn = ty + i * 8;
    OT[(size_t)(n0 + nn) * 1024 + k0 + tx] = (bf16)tile[tx][nn];
  }
}

// ---- fused QKV GEMM, uniform 1024-block 1D grid (4 blocks/CU exactly).
// id<768: KV block (col 1024+{id&15}*128, row {id>>4}*128 of kvin).
// id>=768: Q block (col {q&7}*128, self rows only: row-blocks 0-15 -> b0,
//   16-31 -> b1 i.e. +8 skip of ctx rows). XCD: col residue follows id&7.
// Outputs: Qb (scaled 0.125*log2e), Kb, Vt transposed [2][1024][3072].
__global__ __launch_bounds__(256) void gemm_qkv(
    const bf16* __restrict__ A, const bf16* __restrict__ Bt,
    const float* __restrict__ bq, const float* __restrict__ bkv,
    bf16* __restrict__ Qb, bf16* __restrict__ Kb, bf16* __restrict__ Vt) {
  int id = blockIdx.x;
  int col0, row0;
  if (id < 768) {
    col0 = 1024 + ((id & 15) << 7);
    row0 = (id >> 4) << 7;
  } else {
    int q = id - 768;
    col0 = (q & 7) << 7;
    int r = q >> 3;
    row0 = (r < 16 ? r : r + 8) << 7;
  }
  __shared__ bf16 As[128 * 32];
  __shared__ bf16 Bs[128 * 32];
  int tid = threadIdx.x;
  int wave = tid >> 6, lane = tid & 63;
  int lane15 = lane & 15, quad = lane >> 4;
  int wm = (wave & 1) * 64, wn = (wave >> 1) * 64;
  int rA = lane >> 2;
  int cA = (lane & 3) * 8;
  floatx4 acc[4][4] = {};
  for (int k0 = 0; k0 < 1024; k0 += 32) {
    for (int j = 0; j < 2; j++) {
      int chunk = wave * 2 + j;
      async_ld16(A + (size_t)(row0 + chunk * 16 + rA) * 1024 + k0 + cA,
                 &As[chunk * 512]);
      async_ld16(Bt + (size_t)(col0 + chunk * 16 + rA) * 1024 + k0 + cA,
                 &Bs[chunk * 512]);
    }
    __syncthreads();
    bf16x8 af[4], bfr[4];
    for (int t = 0; t < 4; t++)
      af[t] = *(const bf16x8*)(&As[(wm + t * 16 + lane15) * 32 + quad * 8]);
    for (int t = 0; t < 4; t++)
      bfr[t] = *(const bf16x8*)(&Bs[(wn + t * 16 + lane15) * 32 + quad * 8]);
    for (int tm = 0; tm < 4; tm++)
      for (int tn = 0; tn < 4; tn++)
        acc[tm][tn] = mfma16(af[tm], bfr[tn], acc[tm][tn]);
    __syncthreads();
  }
  float bv[4];
  for (int tn = 0; tn < 4; tn++) {
    int col = col0 + wn + tn * 16 + lane15;
    bv[tn] = (col < 1024) ? bq[col] : bkv[col - 1024];
  }
  int bb = row0 / 3072;
  int l0 = row0 - bb * 3072;
  if (col0 < 1024) {           // Q (self rows guaranteed by decode)
    const float SQ = 0.18033688011f;  // 0.125 * log2(e)
    for (int tm = 0; tm < 4; tm++)
      for (int r = 0; r < 4; r++) {
        size_t grow = (size_t)bb * 2048 + l0 + wm + tm * 16 + quad * 4 + r;
        for (int tn = 0; tn < 4; tn++)
          Qb[grow * 1024 + col0 + wn + tn * 16 + lane15] =
              (bf16)((acc[tm][tn][r] + bv[tn]) * SQ);
      }
  } else if (col0 < 2048) {    // K
    for (int tm = 0; tm < 4; tm++)
      for (int r = 0; r < 4; r++) {
        size_t grow = row0 + wm + tm * 16 + quad * 4 + r;
        for (int tn = 0; tn < 4; tn++)
          Kb[grow * 1024 + (col0 - 1024) + wn + tn * 16 + lane15] =
              (bf16)(acc[tm][tn][r] + bv[tn]);
      }
  } else {                     // V, transposed
    for (int tm = 0; tm < 4; tm++) {
      int lr = l0 + wm + tm * 16 + quad * 4;
      for (int tn = 0; tn < 4; tn++) {
        int c = col0 - 2048 + wn + tn * 16 + lane15;
        bf16x4 pk = { (bf16)(acc[tm][tn][0] + bv[tn]),
                      (bf16)(acc[tm][tn][1] + bv[tn]),
                      (bf16)(acc[tm][tn][2] + bv[tn]),
                      (bf16)(acc[tm][tn][3] + bv[tn]) };
        *(bf16x4*)(Vt + ((size_t)bb * 1024 + c) * 3072 + lr) = pk;
      }
    }
  }
}

// ---- O-proj GEMM: 128x64 tiles, grid (16,32) = 512 blocks (2/CU).
// out fp32 [4096][1024] = Ob [4096][1024] @ WoT^T + bo.
__global__ __launch_bounds__(256) void gemm_o(
    const bf16* __restrict__ A, const bf16* __restrict__ Bt,
    const float* __restrict__ bias, float* __restrict__ O) {
  int col0 = blockIdx.x * 64, row0 = blockIdx.y * 128;
  __shared__ bf16 As[128 * 32];
  __shared__ bf16 Bs[64 * 32];
  int tid = threadIdx.x;
  int wave = tid >> 6, lane = tid & 63;
  int lane15 = lane & 15, quad = lane >> 4;
  int wm = (wave & 1) * 64, wn = (wave >> 1) * 32;
  int rA = lane >> 2;
  int cA = (lane & 3) * 8;
  floatx4 acc[4][2] = {};
  for (int k0 = 0; k0 < 1024; k0 += 32) {
    for (int j = 0; j < 2; j++) {
      int chunk = wave * 2 + j;
      async_ld16(A + (size_t)(row0 + chunk * 16 + rA) * 1024 + k0 + cA,
                 &As[chunk * 512]);
    }
    async_ld16(Bt + (size_t)(col0 + wave * 16 + rA) * 1024 + k0 + cA,
               &Bs[wave * 512]);
    __syncthreads();
    bf16x8 af[4], bfr[2];
    for (int t = 0; t < 4; t++)
      af[t] = *(const bf16x8*)(&As[(wm + t * 16 + lane15) * 32 + quad * 8]);
    for (int t = 0; t < 2; t++)
      bfr[t] = *(const bf16x8*)(&Bs[(wn + t * 16 + lane15) * 32 + quad * 8]);
    for (int tm = 0; tm < 4; tm++)
      for (int tn = 0; tn < 2; tn++)
        acc[tm][tn] = mfma16(af[tm], bfr[tn], acc[tm][tn]);
    __syncthreads();
  }
  float bv[2];
  for (int tn = 0; tn < 2; tn++)
    bv[tn] = bias[col0 + wn + tn * 16 + lane15];
  for (int tm = 0; tm < 4; tm++)
    for (int r = 0; r < 4; r++) {
      size_t grow = row0 + wm + tm * 16 + quad * 4 + r;
      for (int tn = 0; tn < 2; tn++)
        O[grow * 1024 + col0 + wn + tn * 16 + lane15] = acc[tm][tn][r] + bv[tn];
    }
}

// ---- flash attention (R6, unchanged): Br=64, intra-block key-split, XCD
// swizzle blk = qt_ord*32 + bh (all q-blocks of one (b,h) on one XCD).
__global__ __launch_bounds__(256, 4) void flash_attn(
    const bf16* __restrict__ Qb, const bf16* __restrict__ Kb,
    const bf16* __restrict__ Vt, bf16* __restrict__ Ob) {
  const int LD = 72;
  __shared__ bf16 Ks[2][64 * LD];   // [grp][key][dh]
  __shared__ bf16 Vs[2][64 * LD];   // [grp][dh][key]
  int tid = threadIdx.x;
  int wave = tid >> 6, lane = tid & 63;
  int qsub = wave & 1, grp = wave >> 1;
  int l31 = lane & 31, half = lane >> 5;
  int blk = blockIdx.x;
  int qt = 31 - (blk >> 5);      // longest first; bh in low bits -> same XCD
  int bh = blk & 31;
  int h = bh & 15, b = bh >> 4;
  int q0 = qt * 64;
  int qw0 = q0 + qsub * 32;
  int qq = qw0 + l31;            // this lane's q (col of S^T)

  const bf16* qrow = Qb + ((size_t)(b * 2048 + qq)) * 1024 + h * 64 + half * 8;
  bf16x8 qf[4];
  for (int c = 0; c < 4; c++) qf[c] = *(const bf16x8*)(qrow + c * 16);

  floatx16 Oacc[2] = {};
  float l_part = 0.f;

  int nself = qt + 1;            // 64-key self tiles
  int T = nself + 16;
  int iters = (T + 1 - grp) >> 1;
  int max_iters = (T + 1) >> 1;
  const bf16* kbase = Kb + (size_t)(b * 3072) * 1024 + h * 64;
  const bf16* vbase = Vt + ((size_t)b * 1024 + h * 64) * 3072;

  int tidg = qsub * 64 + lane;
  int sr = tidg >> 1, sc = (tidg & 1) * 32;
  bf16x8 kreg[4], vreg[4];
  auto prefetch = [&](int t) {
    int keyrow = (t < nself) ? t * 64 : 2048 + (t - nself) * 64;
    const bf16* kp = kbase + (size_t)(keyrow + sr) * 1024 + sc;
    const bf16* vp = vbase + (size_t)sr * 3072 + keyrow + sc;
    for (int j = 0; j < 4; j++) {
      kreg[j] = *(const bf16x8*)(kp + j * 8);
      vreg[j] = *(const bf16x8*)(vp + j * 8);
    }
  };
  int t = grp;
  prefetch(t);

  bf16* ksg = &Ks[grp][0];
  bf16* vsg = &Vs[grp][0];
  for (int it = 0; it < max_iters; it++) {
    bool act = it < iters;
    int keyrow = 0;
    if (act) keyrow = (t < nself) ? t * 64 : 2048 + (t - nself) * 64;
    __syncthreads();
    if (act)
      for (int j = 0; j < 4; j++) {
        *(bf16x8*)(&ksg[sr * LD + sc + j * 8]) = kreg[j];
        *(bf16x8*)(&vsg[sr * LD + sc + j * 8]) = vreg[j];
      }
    __syncthreads();
    if (act && t + 2 < T) prefetch(t + 2);
    if (act) {
      bool is_self = t < nself;
      uintx4 pf[4];
      for (int kt = 0; kt < 2; kt++) {
        floatx16 st = {};
        const bf16* ka = &ksg[(kt * 32 + l31) * LD + half * 8];
        for (int c = 0; c < 4; c++)
          st = mfma32(*(const bf16x8*)(ka + c * 16), qf[c], st);
        bool need_mask = is_self && (keyrow + kt * 32 + 31 > qw0);
        float p[16];
        for (int r = 0; r < 16; r++) {
          float e = __builtin_amdgcn_exp2f(st[r]);
          if (need_mask) {
            int key = keyrow + kt * 32 + (r & 3) + 8 * (r >> 2) + half * 4;
            if (key > qq) e = 0.f;
          }
          p[r] = e;
          l_part += e;
        }
        unsigned pk[8];
        for (int m2 = 0; m2 < 8; m2++) {
          bf16x2 two = { (bf16)p[2 * m2], (bf16)p[2 * m2 + 1] };
          pk[m2] = __builtin_bit_cast(unsigned, two);
        }
        for (int c2 = 0; c2 < 2; c2++) {
          unsigned a0 = pk[4 * c2 + 0], a1 = pk[4 * c2 + 1];
          unsigned a2 = pk[4 * c2 + 2], a3 = pk[4 * c2 + 3];
          unsigned sA = (unsigned)__shfl_xor((int)(half ? a0 : a2), 32, 64);
          unsigned sB = (unsigned)__shfl_xor((int)(half ? a1 : a3), 32, 64);
          int c = kt * 2 + c2;
          pf[c][0] = half ? sA : a0;
          pf[c][1] = half ? sB : a1;
          pf[c][2] = half ? a2 : sA;
          pf[c][3] = half ? a3 : sB;
        }
      }
      for (int vt = 0; vt < 2; vt++) {
        const bf16* va = &vsg[(vt * 32 + l31) * LD + half * 8];
        for (int c = 0; c < 4; c++)
          Oacc[vt] = mfma32(__builtin_bit_cast(bf16x8, pf[c]),
                            *(const bf16x8*)(va + c * 16), Oacc[vt]);
      }
    }
    t += 2;
  }
  float l_tot = l_part + __shfl_xor(l_part, 32, 64);
  __syncthreads();
  float* Mb = (float*)&Ks[0][0];
  float* Lg = Mb + 4096;
  if (grp == 1) {
    for (int vt = 0; vt < 2; vt++)
      for (int r = 0; r < 16; r++)
        Mb[((qsub * 2 + vt) * 16 + r) * 64 + lane] = Oacc[vt][r];
    if (half == 0) Lg[(2 + qsub) * 32 + l31] = l_tot;
  } else if (half == 0) {
    Lg[qsub * 32 + l31] = l_tot;
  }
  __syncthreads();
  if (grp == 0) {
    for (int vt = 0; vt < 2; vt++)
      for (int r = 0; r < 16; r++) {
        int qr = (r & 3) + 8 * (r >> 2) + half * 4;
        float lsum = Lg[qsub * 32 + qr] + Lg[(2 + qsub) * 32 + qr];
        float o = Oacc[vt][r] + Mb[((qsub * 2 + vt) * 16 + r) * 64 + lane];
        Ob[(size_t)(b * 2048 + qw0 + qr) * 1024 + h * 64 + vt * 32 + l31] =
            (bf16)(o / lsum);
      }
  }
}

extern "C" void kernel_launch(void* const* d_in, const int* in_sizes, int n_in,
                              void* d_out, int out_size, void* d_ws,
                              size_t ws_size, hipStream_t stream) {
  const float* x   = (const float*)d_in[0];
  const float* ctx = (const float*)d_in[1];
  const float* Wq  = (const float*)d_in[2];
  const float* bq  = (const float*)d_in[3];
  const float* Wkv = (const float*)d_in[4];
  const float* bkv = (const float*)d_in[5];
  const float* Wo  = (const float*)d_in[6];
  const float* bo  = (const float*)d_in[7];
  float* out = (float*)d_out;

  bf16* p = (bf16*)d_ws;
  bf16* kvin = p;   p += (size_t)6144 * 1024;      // x||context bf16
  bf16* WT   = p;   p += (size_t)3072 * 1024;      // WqT | WkvT
  bf16* WoT  = p;   p += (size_t)1024 * 1024;
  bf16* Qb   = p;   p += (size_t)4096 * 1024;
  bf16* Kb   = p;   p += (size_t)6144 * 1024;
  bf16* Vt   = p;   p += (size_t)2 * 1024 * 3072;  // V transposed [b][dh][l]
  bf16* Ob   = p;

  prep<<<10240, 256, 0, stream>>>(x, ctx, Wq, Wkv, Wo, kvin, WT, WoT);
  gemm_qkv<<<1024, 256, 0, stream>>>(kvin, WT, bq, bkv, Qb, Kb, Vt);
  flash_attn<<<1024, 256, 0, stream>>>(Qb, Kb, Vt, Ob);
  gemm_o<<<dim3(16, 32), 256, 0, stream>>>(Ob, WoT, bo, out);
}